// Round 1
// baseline (172.739 us; speedup 1.0000x reference)
//
#include <hip/hip_runtime.h>
#include <hip/hip_bf16.h>

typedef __bf16 bf16x8 __attribute__((ext_vector_type(8)));
typedef float  f32x4  __attribute__((ext_vector_type(4)));

#define NHEAD 5
#define FHD   64

// ---------------- kernel 0: x fp32 [b][c][d][hw] -> xbf bf16 [ls][p][c] ----------------
__global__ __launch_bounds__(256) void k0_xpose(const float* __restrict__ x,
                                                __bf16* __restrict__ xbf,
                                                int slice_base) {
  int blk = blockIdx.x;
  int ls = blk >> 4;           // local slice in chunk
  int pt = blk & 15;           // 256-position tile
  int g  = slice_base + ls;
  int b = g >> 3, d = g & 7;
  __shared__ __attribute__((aligned(16))) float xs[64][257];
  const int t = threadIdx.x;
  const int wv = t >> 6, l = t & 63;
  const float* xbase = x + (((size_t)b * 64) * 8 + d) * 4096 + pt * 256;
  // coalesced load: 64 rows (c) x 256 cols (p) fp32
  for (int i = 0; i < 16; ++i) {
    int row = i * 4 + wv;
    int col = l * 4;
    float4 v = *(const float4*)(xbase + (size_t)row * 32768 + col);
    xs[row][col + 0] = v.x; xs[row][col + 1] = v.y;
    xs[row][col + 2] = v.z; xs[row][col + 3] = v.w;
  }
  __syncthreads();
  // coalesced bf16 store: xbf[(ls*4096 + pt*256 + p)*64 + c]
  for (int i = 0; i < 8; ++i) {
    int chunk = i * 256 + t;
    int p = chunk >> 3, cb = chunk & 7;
    bf16x8 o;
    for (int j = 0; j < 8; ++j) o[j] = (__bf16)xs[cb * 8 + j][p];
    *(bf16x8*)(xbf + ((size_t)ls * 4096 + pt * 256 + p) * 64 + cb * 8) = o;
  }
}

// ---------------- kernel 1: qkv[ls][o][hw] = W[o][c] * x[c][hw] + bias[o] ----------------
__global__ __launch_bounds__(256) void k1_qkv(const __bf16* __restrict__ xbf,
                                              const float* __restrict__ W,
                                              const float* __restrict__ bias,
                                              __bf16* __restrict__ qkv,
                                              int slice_base) {
  int blk = blockIdx.x;
  int ls = blk / 240;
  int r  = blk % 240;
  int ot = r >> 4;             // 15 o-tiles of 64 channels
  int pt = r & 15;             // 16 p-tiles of 256 positions
  int o0 = ot * 64;
  __shared__ __attribute__((aligned(16))) __bf16 wlds[64 * 72];
  __shared__ float blds[64];
  __shared__ __attribute__((aligned(16))) __bf16 xt[256 * 72];   // reused as repack buf
  const int t = threadIdx.x;
  // stage W tile 64x64 -> bf16
  for (int i = 0; i < 4; ++i) {
    int e = i * 1024 + t * 4;
    int row = e >> 6, col = e & 63;
    float4 v = *(const float4*)(W + (size_t)o0 * 64 + e);
    __bf16* dst = wlds + row * 72 + col;
    dst[0] = (__bf16)v.x; dst[1] = (__bf16)v.y; dst[2] = (__bf16)v.z; dst[3] = (__bf16)v.w;
  }
  if (t < 64) blds[t] = bias[o0 + t];
  // stage xT tile [256 p][64 c] from xbf (already p-major)
  const __bf16* xsrc = xbf + (size_t)ls * 262144 + (size_t)pt * 16384;
  for (int i = 0; i < 8; ++i) {
    int e = (i * 256 + t) * 8;
    int p = e >> 6, c0 = e & 63;
    *(bf16x8*)(xt + p * 72 + c0) = *(const bf16x8*)(xsrc + e);
  }
  __syncthreads();
  const int wv = t >> 6, l = t & 63;
  const int lr = l & 15, g4 = l >> 4;
  const f32x4 zero4 = {0.f, 0.f, 0.f, 0.f};
  bf16x8 a0 = *(const bf16x8*)(wlds + (16 * wv + lr) * 72 + g4 * 8);
  bf16x8 a1 = *(const bf16x8*)(wlds + (16 * wv + lr) * 72 + 32 + g4 * 8);
  f32x4 acc[16];
  for (int i = 0; i < 16; ++i) acc[i] = zero4;
  for (int p2 = 0; p2 < 16; ++p2) {
    const __bf16* xrow = xt + (p2 * 16 + lr) * 72 + g4 * 8;
    bf16x8 b0 = *(const bf16x8*)(xrow);
    bf16x8 b1 = *(const bf16x8*)(xrow + 32);
    acc[p2] = __builtin_amdgcn_mfma_f32_16x16x32_bf16(a0, b0, acc[p2], 0, 0, 0);
    acc[p2] = __builtin_amdgcn_mfma_f32_16x16x32_bf16(a1, b1, acc[p2], 0, 0, 0);
  }
  float bv[4];
  for (int rr = 0; rr < 4; ++rr) bv[rr] = blds[16 * wv + 4 * g4 + rr];
  __syncthreads();                       // everyone done reading xt/wlds
  __bf16* rp = xt;                       // repack as [64 o][264 p]
  for (int p2 = 0; p2 < 16; ++p2)
    for (int rr = 0; rr < 4; ++rr) {
      int o_l = 16 * wv + 4 * g4 + rr;
      rp[o_l * 264 + p2 * 16 + lr] = (__bf16)(acc[p2][rr] + bv[rr]);
    }
  __syncthreads();
  // coalesced stores
  for (int i = 0; i < 8; ++i) {
    int chunk = i * 256 + t;
    int row = chunk >> 5, cb = chunk & 31;
    bf16x8 v = *(const bf16x8*)(rp + row * 264 + cb * 8);
    *(bf16x8*)(qkv + ((size_t)ls * 960 + o0 + row) * 4096 + (size_t)pt * 256 + cb * 8) = v;
  }
}

// ---------------- kernel 2: per-(slice, head, channel) attention ----------------
__global__ __launch_bounds__(256) void k2_attn(const __bf16* __restrict__ qkv,
                                               const float* __restrict__ x,
                                               const float* __restrict__ gamma,
                                               float* __restrict__ out,
                                               int slice_base) {
  int blk = blockIdx.x;
  int ls = blk / 320;
  int r  = blk % 320;
  int n  = r >> 6;             // head
  int c  = r & 63;             // channel within head
  int g = slice_base + ls;
  int b = g >> 3, d = g & 7;
  __shared__ __attribute__((aligned(16))) __bf16 qlds[64 * 72];
  __shared__ __attribute__((aligned(16))) __bf16 klds[64 * 72];
  __shared__ __attribute__((aligned(16))) __bf16 vt[64 * 72];   // V transposed [w][j]
  __shared__ __attribute__((aligned(16))) __bf16 attl[64 * 72];
  const int t = threadIdx.x;
  const __bf16* qp = qkv + ((size_t)ls * 960 + n * 192 + c) * 4096;
  const __bf16* kp = qp + (size_t)64 * 4096;
  const __bf16* vp = qp + (size_t)128 * 4096;
  {
    int row = t >> 2, c0 = (t & 3) * 16;
    *(bf16x8*)(qlds + row * 72 + c0)     = *(const bf16x8*)(qp + row * 64 + c0);
    *(bf16x8*)(qlds + row * 72 + c0 + 8) = *(const bf16x8*)(qp + row * 64 + c0 + 8);
    *(bf16x8*)(klds + row * 72 + c0)     = *(const bf16x8*)(kp + row * 64 + c0);
    *(bf16x8*)(klds + row * 72 + c0 + 8) = *(const bf16x8*)(kp + row * 64 + c0 + 8);
    bf16x8 v0 = *(const bf16x8*)(vp + row * 64 + c0);
    bf16x8 v1 = *(const bf16x8*)(vp + row * 64 + c0 + 8);
    for (int i = 0; i < 8; ++i) vt[(c0 + i) * 72 + row]     = v0[i];
    for (int i = 0; i < 8; ++i) vt[(c0 + 8 + i) * 72 + row] = v1[i];
  }
  __syncthreads();
  const int wv = t >> 6, l = t & 63;
  const int lr = l & 15, g4 = l >> 4;
  const int i0 = wv * 16;
  const f32x4 zero4 = {0.f, 0.f, 0.f, 0.f};
  // sim[i][j] = sum_w K[i][w] * Q[j][w]
  f32x4 sacc[4];
  for (int i = 0; i < 4; ++i) sacc[i] = zero4;
  {
    bf16x8 a0 = *(const bf16x8*)(klds + (i0 + lr) * 72 + g4 * 8);
    bf16x8 a1 = *(const bf16x8*)(klds + (i0 + lr) * 72 + 32 + g4 * 8);
    for (int jt = 0; jt < 4; ++jt) {
      bf16x8 b0 = *(const bf16x8*)(qlds + (jt * 16 + lr) * 72 + g4 * 8);
      bf16x8 b1 = *(const bf16x8*)(qlds + (jt * 16 + lr) * 72 + 32 + g4 * 8);
      sacc[jt] = __builtin_amdgcn_mfma_f32_16x16x32_bf16(a0, b0, sacc[jt], 0, 0, 0);
      sacc[jt] = __builtin_amdgcn_mfma_f32_16x16x32_bf16(a1, b1, sacc[jt], 0, 0, 0);
    }
  }
  // row softmax over j: row = i0 + 4*g4 + rr, cols spread over jt (frags) x lr (lanes)
  float pr[4][4];
  for (int rr = 0; rr < 4; ++rr) {
    float m = fmaxf(fmaxf(sacc[0][rr], sacc[1][rr]), fmaxf(sacc[2][rr], sacc[3][rr]));
    for (int dd = 1; dd < 16; dd <<= 1) m = fmaxf(m, __shfl_xor(m, dd));
    float s = 0.f;
    for (int jt = 0; jt < 4; ++jt) { pr[jt][rr] = __expf(sacc[jt][rr] - m); s += pr[jt][rr]; }
    for (int dd = 1; dd < 16; dd <<= 1) s += __shfl_xor(s, dd);
    float inv = 1.0f / s;
    for (int jt = 0; jt < 4; ++jt) pr[jt][rr] *= inv;
  }
  for (int jt = 0; jt < 4; ++jt)
    for (int rr = 0; rr < 4; ++rr)
      attl[(i0 + 4 * g4 + rr) * 72 + jt * 16 + lr] = (__bf16)pr[jt][rr];
  __syncthreads();
  // pv[i][w] = sum_j att[i][j] * V[j][w]   (B-operand from vt = V^T)
  f32x4 pv[4];
  for (int i = 0; i < 4; ++i) pv[i] = zero4;
  {
    bf16x8 a0 = *(const bf16x8*)(attl + (i0 + lr) * 72 + g4 * 8);
    bf16x8 a1 = *(const bf16x8*)(attl + (i0 + lr) * 72 + 32 + g4 * 8);
    for (int wt = 0; wt < 4; ++wt) {
      bf16x8 b0 = *(const bf16x8*)(vt + (wt * 16 + lr) * 72 + g4 * 8);
      bf16x8 b1 = *(const bf16x8*)(vt + (wt * 16 + lr) * 72 + 32 + g4 * 8);
      pv[wt] = __builtin_amdgcn_mfma_f32_16x16x32_bf16(a0, b0, pv[wt], 0, 0, 0);
      pv[wt] = __builtin_amdgcn_mfma_f32_16x16x32_bf16(a1, b1, pv[wt], 0, 0, 0);
    }
  }
  // epilogue: channel shuffle + gamma + residual
  int o2 = c * NHEAD + n;
  int np = o2 >> 6, fp = o2 & 63;
  int oc = fp * NHEAD + np;
  float gm = gamma[np];
  const float* xp = x + (((size_t)b * 64 + fp) * 8 + d) * 4096;
  float* op = out + (((size_t)b * 320 + oc) * 8 + d) * 4096;
  for (int wt = 0; wt < 4; ++wt)
    for (int rr = 0; rr < 4; ++rr) {
      int i = i0 + 4 * g4 + rr;
      int w = wt * 16 + lr;
      int idx = i * 64 + w;
      op[idx] = gm * pv[wt][rr] + xp[idx];
    }
}

extern "C" void kernel_launch(void* const* d_in, const int* in_sizes, int n_in,
                              void* d_out, int out_size, void* d_ws, size_t ws_size,
                              hipStream_t stream) {
  const float* x     = (const float*)d_in[0];
  const float* W     = (const float*)d_in[1];
  const float* bias  = (const float*)d_in[2];
  const float* gamma = (const float*)d_in[3];
  float* out = (float*)d_out;

  // per (b,d) slice: xbf = 4096*64*2 = 524288 B ; qkv = 960*4096*2 = 7864320 B
  const size_t per_slice = 524288 + 7864320;   // 8 MB
  int S = (int)(ws_size / per_slice);
  if (S > 32) S = 32;
  if (S < 1)  S = 1;                            // assume ws_size >= 8 MB
  __bf16* xbf = (__bf16*)d_ws;
  __bf16* qkv = (__bf16*)((char*)d_ws + (size_t)S * 524288);

  for (int sb = 0; sb < 32; sb += S) {
    int sc = 32 - sb; if (sc > S) sc = S;
    k0_xpose<<<16  * sc, 256, 0, stream>>>(x, xbf, sb);
    k1_qkv  <<<240 * sc, 256, 0, stream>>>(xbf, W, bias, qkv, sb);
    k2_attn <<<320 * sc, 256, 0, stream>>>(qkv, x, gamma, out, sb);
  }
}